// Round 5
// baseline (168.595 us; speedup 1.0000x reference)
//
#include <hip/hip_runtime.h>
#include <hip/hip_fp16.h>
#include <math.h>

// ShadowMapping forward: hard + soft (Fourier-basis, blurred) shadow maps.
// R5 (= R4 + compile fix): HW v_sin/v_cos + harmonic recurrence, +-2/ck
//     folded into fp16 D channels, register-vertical + packed-fp16
//     LDS-horizontal blur, no setup kernel, XCD-affinity light swizzle.
//     Hard-path geometry chain bit-identical to R2/R3 (validated).

#define RESN 512
#define NL 16
#define NPIX (RESN*RESN)
#define BW 256          // output columns per build block
#define BH4 4           // output rows per build block
#define BC (BW+4)       // columns incl. 2+2 halo

#define CK1 3.14159265358979323846f
#define CK3 9.42477796076937971538f
#define CK5 15.7079632679489661923f
#define CK7 21.9911485751285526692f

typedef __fp16 fp16x2_t __attribute__((ext_vector_type(2)));

static __device__ __forceinline__ __half2 pkrtz(float a, float b) {
  union { fp16x2_t f; __half2 h; } u;
  u.f = __builtin_amdgcn_cvt_pkrtz(a, b);
  return u.h;
}

// sin/cos of (3,5,7)*x from sin/cos of x via angle addition.
// s1=c1=0 input (zero padding) propagates 0 to all outputs.
static __device__ __forceinline__ void harm8(float s1, float c1,
    float& s3, float& c3, float& s5, float& c5, float& s7, float& c7) {
  float s2 = 2.0f*s1*c1;
  float c2 = 1.0f - 2.0f*s1*s1;
  s3 = s2*c1 + c2*s1;  c3 = c2*c1 - s2*s1;
  s5 = s3*c2 + c3*s2;  c5 = c3*c2 - s3*s2;
  s7 = s5*c2 + c5*s2;  c7 = c5*c2 - s5*s2;
}

// 5-tap truncated (tails < 2e-12), 21-tap-normalized Gaussian weights.
static __device__ __forceinline__ void blur_w(float sg, float* w) {
  float sig = ((2.0f * (6.0f * sg + 1.0f)) - 1.0f) / 6.0f;
  float ksum = 0.0f, kmid[5];
  for (int i = 0; i < 21; ++i) {
    float t = (float)(i - 10);
    float r = t / sig;
    float e = expf(-0.5f * (r * r));
    ksum += e;
    if (i >= 8 && i <= 12) kmid[i-8] = e;
  }
  for (int k = 0; k < 5; ++k) w[k] = kmid[k] / ksum;
}

// Build blurred, coefficient-folded basis:
// D[2m] = (-2/ck_m)*blur(cos(ck_m z)), D[2m+1] = (2/ck_m)*blur(sin(ck_m z)),
// packed 8 x fp16 = 16B per shadow texel.
__global__ __launch_bounds__(256) void build_kernel(
    const float* __restrict__ z_map,
    const float* __restrict__ als,
    uint4* __restrict__ dmap)
{
  __shared__ uint4 vb[BH4][BC];   // vertically blurred, fp16x8 packed
  const int l  = (int)blockIdx.z;
  const int by = (int)blockIdx.y * BH4;
  const int bx = (int)blockIdx.x * BW;
  const int t  = (int)threadIdx.x;
  const int zb = l << 18;
  float w[5];
  blur_w(als[l*7+3], w);
  const float A0 = -2.0f/CK1, B0 = 2.0f/CK1;
  const float A1 = -2.0f/CK3, B1 = 2.0f/CK3;
  const float A2 = -2.0f/CK5, B2 = 2.0f/CK5;
  const float A3 = -2.0f/CK7, B3 = 2.0f/CK7;

  auto vert = [&](int c) {
    int x = bx - 2 + c;
    bool xok = (x >= 0 && x < RESN);
    float R[8][8];
    #pragma unroll
    for (int rI = 0; rI < 8; ++rI) {
      int gy = by - 2 + rI;
      float s1 = 0.0f, c1 = 0.0f;
      if (xok && gy >= 0 && gy < RESN) {
        float z = z_map[zb + (gy<<9) + x];
        s1 = __builtin_amdgcn_sinf(0.5f*z);   // sin(pi*z), v_sin takes revs
        c1 = __builtin_amdgcn_cosf(0.5f*z);
      }
      float s3,c3,s5,c5,s7,c7;
      harm8(s1, c1, s3, c3, s5, c5, s7, c7);
      R[rI][0] = A0*c1; R[rI][1] = B0*s1;
      R[rI][2] = A1*c3; R[rI][3] = B1*s3;
      R[rI][4] = A2*c5; R[rI][5] = B2*s5;
      R[rI][6] = A3*c7; R[rI][7] = B3*s7;
    }
    #pragma unroll
    for (int o = 0; o < BH4; ++o) {
      union { __half2 h2[4]; uint4 u; } pk;
      #pragma unroll
      for (int ch = 0; ch < 8; ch += 2) {
        float a = w[0]*(R[o][ch]  +R[o+4][ch])
                + w[1]*(R[o+1][ch]+R[o+3][ch]) + w[2]*R[o+2][ch];
        float b = w[0]*(R[o][ch+1]  +R[o+4][ch+1])
                + w[1]*(R[o+1][ch+1]+R[o+3][ch+1]) + w[2]*R[o+2][ch+1];
        pk.h2[ch>>1] = pkrtz(a, b);
      }
      vb[o][c] = pk.u;
    }
  };
  vert(t);
  if (t < 4) vert(BW + t);
  __syncthreads();

  __half2 wh[5];
  #pragma unroll
  for (int k = 0; k < 5; ++k) wh[k] = pkrtz(w[k], w[k]);
  #pragma unroll
  for (int o = 0; o < BH4; ++o) {
    union { __half2 h2[4]; uint4 u; } acc, tap;
    tap.u = vb[o][t];
    #pragma unroll
    for (int j = 0; j < 4; ++j) acc.h2[j] = __hmul2(wh[0], tap.h2[j]);
    #pragma unroll
    for (int k = 1; k < 5; ++k) {
      tap.u = vb[o][t + k];
      #pragma unroll
      for (int j = 0; j < 4; ++j) acc.h2[j] = __hfma2(wh[k], tap.h2[j], acc.h2[j]);
    }
    dmap[(l<<18) + ((by+o)<<9) + (bx+t)] = acc.u;
  }
}

__global__ __launch_bounds__(256) void main_kernel(
    const float* __restrict__ depth,
    const float* __restrict__ mask,
    const float* __restrict__ z_map,
    const float* __restrict__ als,
    const uint4* __restrict__ dmap,
    float* __restrict__ out,
    float TANHF, float OZF, float OWF, int mode)
{
  #pragma clang fp contract(off)
  const float OFFS = -0.0642233295781f;
  const float CLB  = 0.4458709375254f;
  // XCD-affinity swizzle: block id === light (mod 8) so each light's 4MB
  // dmap slice + 1MB z slice is L2-resident on one XCD.
  const int id = (int)blockIdx.x;
  const int l  = ((id >> 13) << 3) | (id & 7);
  const int pb = (id >> 3) & 1023;
  const int p  = (pb << 8) + (int)threadIdx.x;
  const int r = p >> 9, c = p & 511;
  // per-light geometry coefficients (uniform; identical expressions/order to
  // R2's setup kernel -> bit-identical hard path)
  float xd = als[l*7+0], yd = als[l*7+1], zd = als[l*7+2];
  float cosp = sqrtf(xd*xd + zd*zd);
  float cost = zd / cosp;
  float sint = xd / cosp;
  float e00 = cost,          e02 = -sint;
  float e10 = (-sint)*yd,    e11 = cosp,  e12 = (-cost)*yd;
  float e20 = cosp*sint,     e21 = yd,    e22 = cosp*cost;

  float dz = depth[p];
  float mk = mask[p];
  float m1c = 2.0f * ((float)c / 512.0f + 0.0009765625f) - 1.0f;
  float m1r = 2.0f * ((float)r / 512.0f + 0.0009765625f) - 1.0f;
  float tT = dz * TANHF;
  float qx = tT * m1c;
  float qy = tT * m1r;
  float qz = 2.7f - dz;
  // XLA dot emitter: sequential fmuladd over w (validated R2)
  float X1 = fmaf(qz, e02, qx * e00);
  float Y1 = fmaf(qz, e12, fmaf(qy, e11, qx * e10));
  float T2 = fmaf(qz, e22, fmaf(qy, e21, qx * e20));
  float Z1 = T2 + (-2.7f);
  float ZZ = (Z1 * OZF) + OWF;
  float uf = (X1 + 1.0f) * 256.0f;
  float vf = (Y1 + 1.0f) * 256.0f;
  int u = (int)uf; u = u < 0 ? 0 : (u > 511 ? 511 : u);
  int v = (int)vf; v = v < 0 ? 0 : (v > 511 ? 511 : v);
  float dd = 0.5f * (1.0f + ZZ);
  dd = fminf(fmaxf(dd, 0.0f), 1.0f);
  int zi = (l<<18) + (v<<9) + u;
  float dpo = dd + OFFS;
  float zg = z_map[zi];
  float q = 0.0f;
  if (mode == 2) {
    // fallback: direct 25-tap, sum_n a_n B_n = sum_m (2/ck) sin(ck(z-dpo))
    float w5[5];
    blur_w(als[l*7+3], w5);
    for (int ty = -2; ty <= 2; ++ty) {
      int yy = v + ty; if (yy < 0 || yy >= RESN) continue;
      for (int tx = -2; tx <= 2; ++tx) {
        int xx = u + tx; if (xx < 0 || xx >= RESN) continue;
        float z = z_map[(l<<18)+(yy<<9)+xx];
        float wgt = w5[ty+2]*w5[tx+2];
        float acc = (2.0f/CK1) * sinf(CK1*(z - dpo));
        acc += (2.0f/CK3) * sinf(CK3*(z - dpo));
        acc += (2.0f/CK5) * sinf(CK5*(z - dpo));
        acc += (2.0f/CK7) * sinf(CK7*(z - dpo));
        q += wgt * acc;
      }
    }
  } else {
    union { uint4 u4; __half h[8]; } W;
    W.u4 = dmap[zi];
    float s1 = __builtin_amdgcn_sinf(0.5f*dpo);  // sin(pi*dpo)
    float c1 = __builtin_amdgcn_cosf(0.5f*dpo);
    float s3,c3,s5,c5,s7,c7;
    harm8(s1, c1, s3, c3, s5, c5, s7, c7);
    // D channels carry +-2/ck already
    q = fmaf(s1, __half2float(W.h[0]), q);
    q = fmaf(c1, __half2float(W.h[1]), q);
    q = fmaf(s3, __half2float(W.h[2]), q);
    q = fmaf(c3, __half2float(W.h[3]), q);
    q = fmaf(s5, __half2float(W.h[4]), q);
    q = fmaf(c5, __half2float(W.h[5]), q);
    q = fmaf(s7, __half2float(W.h[6]), q);
    q = fmaf(c7, __half2float(W.h[7]), q);
  }
  float diff = fmaxf(dd - zg, 0.0f);
  float hard = (diff > 0.008f) ? 0.0f : 1.0f;
  out[(l<<18) + p] = mk * hard;
  float qc = fminf(fmaxf(q, -CLB), CLB) / CLB;
  float sf = 0.5f * (qc + 1.0f);
  sf = fminf(fmaxf(sf, 0.0f), 1.0f);
  out[(NL<<18) + (l<<18) + p] = mk * sf;
}

extern "C" void kernel_launch(void* const* d_in, const int* in_sizes, int n_in,
                              void* d_out, int out_size, void* d_ws, size_t ws_size,
                              hipStream_t stream) {
  (void)in_sizes; (void)n_in; (void)out_size;
  const float* depth = (const float*)d_in[0];
  const float* als   = (const float*)d_in[1];
  const float* mask  = (const float*)d_in[2];
  const float* z_map = (const float*)d_in[3];
  float* out = (float*)d_out;
  uint4* dmap = (uint4*)d_ws;
  // constants in double, replicating numpy, then rounded to f32
  double TANH = tan(2.0*atan(0.5*36.0/50.0)/2.0);
  double NEARc = 2.7 - sqrt(2.0)*2.7*TANH;
  double FARc  = 2.7 + sqrt(2.0)*2.7*TANH;
  float ozf = (float)(-2.0/(FARc-NEARc));
  float owf = (float)((-(FARc+NEARc))/(FARc-NEARc));
  float tanhf_ = (float)TANH;
  size_t need = (size_t)NL*NPIX*16;
  int mode = (ws_size >= need) ? 1 : 2;

  if (mode != 2) {
    dim3 gB(RESN/BW, RESN/BH4, NL);
    build_kernel<<<gB, 256, 0, stream>>>(z_map, als, dmap);
  }
  main_kernel<<<NL*NPIX/256, 256, 0, stream>>>(depth, mask, z_map, als, dmap,
                                               out, tanhf_, ozf, owf, mode);
}

// Round 6
// 151.460 us; speedup vs baseline: 1.1131x; 1.1131x over previous
//
#include <hip/hip_runtime.h>
#include <math.h>

// ShadowMapping forward: hard + soft shadow maps, fully fused.
// R6: no intermediate D_map at all. Soft = direct 3x3 Gaussian-weighted sum of
//     f(z) = (2/pi) * sum_m (1/m) sin(m*pi*(z - dpo)), m in {1,3,5,7}, via one
//     HW v_sin/v_cos + harmonic recurrence per tap. 3x3 suffices: sigma <=
//     0.407 -> tap-2 weight e1^4 <= 6e-6 (kept in the normalization, taps
//     dropped; error ~1e-5 << 1.8e-2 tol). OOB taps get zero WEIGHT (matches
//     conv zero-padding); indices clamped so all 9 loads are unconditional.
//     Center tap doubles as zg. Hard-path geometry chain bit-identical to
//     R2/R3/R5 (validated: XLA dot emitter = sequential fmuladd over w).

#define RESN 512
#define NL 16
#define NPIX (RESN*RESN)

__global__ __launch_bounds__(256) void fused_kernel(
    const float* __restrict__ depth,
    const float* __restrict__ mask,
    const float* __restrict__ z_map,
    const float* __restrict__ als,
    float* __restrict__ out,
    float TANHF, float OZF, float OWF)
{
  #pragma clang fp contract(off)
  const float OFFS = -0.0642233295781f;
  const float CLB  = 0.4458709375254f;
  const float TWO_OVER_PI = 0.63661977236758134308f;
  // XCD-affinity swizzle: block id === light (mod 8); each light's 1MB z
  // slice stays L2-resident on one XCD.
  const int id = (int)blockIdx.x;
  const int l  = ((id >> 13) << 3) | (id & 7);
  const int pb = (id >> 3) & 1023;
  const int p  = (pb << 8) + (int)threadIdx.x;
  const int r = p >> 9, c = p & 511;

  // ---- per-light uniforms ----------------------------------------------
  float xd = als[l*7+0], yd = als[l*7+1], zd = als[l*7+2], sg = als[l*7+3];
  float cosp = sqrtf(xd*xd + zd*zd);
  float cost = zd / cosp;
  float sint = xd / cosp;
  float e00 = cost,          e02 = -sint;
  float e10 = (-sint)*yd,    e11 = cosp,  e12 = (-cost)*yd;
  float e20 = cosp*sint,     e21 = yd,    e22 = cosp*cost;
  // blur weights: radius-1, normalized over the full 21-tap sum
  // (e2 = e1^4 exactly; e3.. < 2e-12 ignored)
  float sig = ((2.0f*(6.0f*sg + 1.0f)) - 1.0f) / 6.0f;
  float ivs = 1.0f/(sig*sig);
  float e1  = __builtin_amdgcn_exp2f(-0.72134752044448170368f*ivs); // exp(-.5/s^2)
  float e1sq = e1*e1;
  float e2  = e1sq*e1sq;
  float kinv = 1.0f/(1.0f + 2.0f*e1 + 2.0f*e2);
  float w0 = kinv, w1 = e1*kinv;

  // ---- geometry (bit-identical to validated chain) ---------------------
  float dz = depth[p];
  float mk = mask[p];
  float m1c = 2.0f * ((float)c / 512.0f + 0.0009765625f) - 1.0f;
  float m1r = 2.0f * ((float)r / 512.0f + 0.0009765625f) - 1.0f;
  float tT = dz * TANHF;
  float qx = tT * m1c;
  float qy = tT * m1r;
  float qz = 2.7f - dz;
  // XLA dot emitter: sequential fmuladd over w (validated R2)
  float X1 = fmaf(qz, e02, qx * e00);
  float Y1 = fmaf(qz, e12, fmaf(qy, e11, qx * e10));
  float T2 = fmaf(qz, e22, fmaf(qy, e21, qx * e20));
  float Z1 = T2 + (-2.7f);
  float ZZ = (Z1 * OZF) + OWF;
  float uf = (X1 + 1.0f) * 256.0f;
  float vf = (Y1 + 1.0f) * 256.0f;
  int u = (int)uf; u = u < 0 ? 0 : (u > 511 ? 511 : u);
  int v = (int)vf; v = v < 0 ? 0 : (v > 511 ? 511 : v);
  float dd = 0.5f * (1.0f + ZZ);
  dd = fminf(fmaxf(dd, 0.0f), 1.0f);
  float dpo = dd + OFFS;

  // ---- 9 tap loads (clamped indices; OOB handled by zero weights) ------
  const int base = l << 18;
  int u0 = u > 0 ? u - 1 : 0;
  int u2 = u < 511 ? u + 1 : 511;
  int v0 = v > 0 ? v - 1 : 0;
  int v2 = v < 511 ? v + 1 : 511;
  const float* zr0 = z_map + base + (v0 << 9);
  const float* zr1 = z_map + base + (v  << 9);
  const float* zr2 = z_map + base + (v2 << 9);
  float zA = zr0[u0], zB = zr0[u], zC = zr0[u2];
  float zD = zr1[u0], zg = zr1[u], zF = zr1[u2];
  float zG = zr2[u0], zH = zr2[u], zI = zr2[u2];

  float wuL = (u > 0)   ? w1 : 0.0f;
  float wuR = (u < 511) ? w1 : 0.0f;
  float wvT = (v > 0)   ? w1 : 0.0f;
  float wvB = (v < 511) ? w1 : 0.0f;

  // f(z) = sum_m (1/m) sin(m*pi*(z-dpo)), m = 1,3,5,7  (x in revolutions)
  auto fval = [&](float z) {
    float x = 0.5f * (z - dpo);
    float s1 = __builtin_amdgcn_sinf(x);
    float c1 = __builtin_amdgcn_cosf(x);
    float s2 = 2.0f*s1*c1;
    float c2 = fmaf(-2.0f*s1, s1, 1.0f);
    float s3 = fmaf(s2, c1,  c2*s1);
    float c3 = fmaf(c2, c1, -(s2*s1));
    float s5 = fmaf(s3, c2,  c3*s2);
    float c5 = fmaf(c3, c2, -(s3*s2));
    float s7 = fmaf(s5, c2,  c5*s2);
    return fmaf(0.14285714285714285f, s7,
           fmaf(0.2f, s5, fmaf(0.3333333333333333f, s3, s1)));
  };

  float rowT = fmaf(wuL, fval(zA), fmaf(w0, fval(zB), wuR * fval(zC)));
  float rowC = fmaf(wuL, fval(zD), fmaf(w0, fval(zg), wuR * fval(zF)));
  float rowB = fmaf(wuL, fval(zG), fmaf(w0, fval(zH), wuR * fval(zI)));
  float q = TWO_OVER_PI * fmaf(wvT, rowT, fmaf(w0, rowC, wvB * rowB));

  // ---- outputs ----------------------------------------------------------
  float diff = fmaxf(dd - zg, 0.0f);
  float hard = (diff > 0.008f) ? 0.0f : 1.0f;
  out[base + p] = mk * hard;
  float qc = fminf(fmaxf(q, -CLB), CLB) / CLB;
  float sf = 0.5f * (qc + 1.0f);
  sf = fminf(fmaxf(sf, 0.0f), 1.0f);
  out[(NL*NPIX) + base + p] = mk * sf;
}

extern "C" void kernel_launch(void* const* d_in, const int* in_sizes, int n_in,
                              void* d_out, int out_size, void* d_ws, size_t ws_size,
                              hipStream_t stream) {
  (void)in_sizes; (void)n_in; (void)out_size; (void)d_ws; (void)ws_size;
  const float* depth = (const float*)d_in[0];
  const float* als   = (const float*)d_in[1];
  const float* mask  = (const float*)d_in[2];
  const float* z_map = (const float*)d_in[3];
  float* out = (float*)d_out;
  // constants in double, replicating numpy, then rounded to f32
  double TANH = tan(2.0*atan(0.5*36.0/50.0)/2.0);
  double NEARc = 2.7 - sqrt(2.0)*2.7*TANH;
  double FARc  = 2.7 + sqrt(2.0)*2.7*TANH;
  float ozf = (float)(-2.0/(FARc-NEARc));
  float owf = (float)((-(FARc+NEARc))/(FARc-NEARc));
  float tanhf_ = (float)TANH;

  fused_kernel<<<NL*NPIX/256, 256, 0, stream>>>(depth, mask, z_map, als, out,
                                                tanhf_, ozf, owf);
}